// Round 1
// 380.507 us; speedup vs baseline: 1.0453x; 1.0453x over previous
//
#include <hip/hip_runtime.h>
#include <math.h>

#define BB 32
#define SS 8192
#define DD 256
#define K_SEL 1638            // max(1, int(8192*0.2))
#define EMPH 1.5f
#define HBINS 2048            // top-11-bit histogram
#define HCH 8                 // chunks per batch (K1 blocks per batch)
#define NCH3 16               // K3 chunks per batch
#define CH3_ROWS (SS / NCH3)  // 512 rows per K3 block
#define NCHUNK 64
#define ROWS_PER_BLOCK (SS / NCHUNK)

__device__ __forceinline__ unsigned monokey(float f) {
    unsigned u = __float_as_uint(f);
    return u ^ ((u & 0x80000000u) ? 0xFFFFFFFFu : 0x80000000u);
}

// ---- K1: e = tanh(x·W+b); 11-bit hist; s1part = sum exp(e)*x; zpart = sum exp(e) ----
__global__ __launch_bounds__(1024) void k1_e_hist_s1(const float* __restrict__ x,
                                                     const float* __restrict__ W,
                                                     const float* __restrict__ bias,
                                                     float* __restrict__ e_ws,
                                                     unsigned* __restrict__ hist_ws,
                                                     float* __restrict__ s1part,
                                                     float* __restrict__ zpart) {
    __shared__ unsigned hist[HBINS];   // 8 KB
    __shared__ float red[16 * 256];    // 16 KB
    __shared__ float zred;
    const int tid = threadIdx.x;
    const int lane = tid & 63;
    const int wv = tid >> 6;
    for (int i = tid; i < HBINS; i += 1024) hist[i] = 0;
    if (tid == 0) zred = 0.0f;

    const int b = blockIdx.x >> 3;
    const int ch = blockIdx.x & 7;
    const int row0 = ch * 1024;

    const float4* W4 = (const float4*)W;
    const int cg = lane & 15;
    const float4 w0 = W4[cg];
    const float4 w1 = W4[cg + 16];
    const float4 w2 = W4[cg + 32];
    const float4 w3 = W4[cg + 48];
    const float bias0 = bias[0];
    __syncthreads();

    const float* xb = x + (size_t)b * SS * DD;
    float* eb = e_ws + (size_t)b * SS;

    float acc[16];
    #pragma unroll
    for (int m = 0; m < 16; m++) acc[m] = 0.0f;
    float zloc = 0.0f;

    for (int it = 0; it < 16; it++) {
        const int r = row0 + (it * 16 + wv) * 4 + (lane >> 4);
        const float4* rp = (const float4*)(xb + (size_t)r * DD);
        float4 a0 = rp[cg];
        float4 a1 = rp[cg + 16];
        float4 a2 = rp[cg + 32];
        float4 a3 = rp[cg + 48];
        float p = a0.x * w0.x + a0.y * w0.y + a0.z * w0.z + a0.w * w0.w;
        p += a1.x * w1.x + a1.y * w1.y + a1.z * w1.z + a1.w * w1.w;
        p += a2.x * w2.x + a2.y * w2.y + a2.z * w2.z + a2.w * w2.w;
        p += a3.x * w3.x + a3.y * w3.y + a3.z * w3.z + a3.w * w3.w;
        p += __shfl_xor(p, 1, 64);
        p += __shfl_xor(p, 2, 64);
        p += __shfl_xor(p, 4, 64);
        p += __shfl_xor(p, 8, 64);
        float ev = tanhf(p + bias0);
        float w = expf(ev);
        if (cg == 0) {
            eb[r] = ev;
            atomicAdd(&hist[monokey(ev) >> 21], 1u);
            zloc += w;
        }
        acc[0] += w * a0.x;  acc[1] += w * a0.y;  acc[2] += w * a0.z;  acc[3] += w * a0.w;
        acc[4] += w * a1.x;  acc[5] += w * a1.y;  acc[6] += w * a1.z;  acc[7] += w * a1.w;
        acc[8] += w * a2.x;  acc[9] += w * a2.y;  acc[10] += w * a2.z; acc[11] += w * a2.w;
        acc[12] += w * a3.x; acc[13] += w * a3.y; acc[14] += w * a3.z; acc[15] += w * a3.w;
    }
    #pragma unroll
    for (int m = 0; m < 16; m++) {
        acc[m] += __shfl_xor(acc[m], 16, 64);
        acc[m] += __shfl_xor(acc[m], 32, 64);
    }
    zloc += __shfl_xor(zloc, 16, 64);
    zloc += __shfl_xor(zloc, 32, 64);
    if (lane == 0) atomicAdd(&zred, zloc);
    if (lane < 16) {
        #pragma unroll
        for (int m = 0; m < 16; m++) red[wv * 256 + lane * 16 + m] = acc[m];
    }
    __syncthreads();
    unsigned* hout = hist_ws + (size_t)blockIdx.x * HBINS;
    for (int i = tid; i < HBINS; i += 1024) hout[i] = hist[i];
    if (tid == 0) zpart[blockIdx.x] = zred;
    if (tid < 256) {
        const int d = tid;
        const int q = d >> 6;
        const int cg2 = (d >> 2) & 15;
        const int j = d & 3;
        const int m = q * 4 + j;
        float s = 0.0f;
        #pragma unroll
        for (int w = 0; w < 16; w++) s += red[w * 256 + cg2 * 16 + m];
        s1part[(size_t)blockIdx.x * DD + d] = s;
    }
}

// ---- K2: threshold-only select: T, r -> per-chunk tie quotas; invZ ----
// (write phase moved to K3; no serialized selCnt atomics here anymore)
__global__ __launch_bounds__(1024) void k2_thresh(const float* __restrict__ e_ws,
                                                  const unsigned* __restrict__ hist_ws,
                                                  const float* __restrict__ zpart,
                                                  float* __restrict__ zinv,
                                                  unsigned* __restrict__ tq_ws) {
    const int b = blockIdx.x;
    const int tid = threadIdx.x;
    const int lane = tid & 63;
    const int wid = tid >> 6;

    __shared__ float se[SS];            // 32 KB
    __shared__ unsigned binTot[HBINS];  // 8 KB
    __shared__ unsigned gsuf[257];
    __shared__ unsigned hsuf[129];
    __shared__ unsigned h7[128];
    __shared__ unsigned tie16[NCH3];
    __shared__ unsigned uvar[2];        // 0: prefix, 1: kk

    const float* eg = e_ws + (size_t)b * SS;

    #pragma unroll
    for (int i = 0; i < 8; i++) {
        int s = tid + i * 1024;
        se[s] = eg[s];
    }
    if (tid == 0) {
        float z = 0.0f;
        #pragma unroll
        for (int c = 0; c < HCH; c++) z += zpart[b * HCH + c];
        zinv[b] = 1.0f / z;
    }
    // merge chunk histograms: thread t owns bins 2t, 2t+1
    unsigned c0 = 0, c1 = 0;
    for (int ch = 0; ch < HCH; ch++) {
        const unsigned* hc = hist_ws + ((size_t)(b * HCH + ch)) * HBINS;
        c0 += hc[2 * tid];
        c1 += hc[2 * tid + 1];
    }
    binTot[2 * tid] = c0;
    binTot[2 * tid + 1] = c1;
    __syncthreads();                                   // B1

    // group-of-8 sums + suffix scan over 256 groups, single wave (lane owns 4 groups)
    if (wid == 0) {
        unsigned g[4];
        unsigned tot = 0;
        #pragma unroll
        for (int j = 0; j < 4; j++) {
            unsigned s = 0;
            #pragma unroll
            for (int m = 0; m < 8; m++) s += binTot[(lane * 4 + j) * 8 + m];
            g[j] = s;
            tot += s;
        }
        unsigned xx = tot;
        #pragma unroll
        for (int off = 1; off < 64; off <<= 1) {
            unsigned v = __shfl_down(xx, off, 64);
            if (lane + off < 64) xx += v;
        }
        unsigned Snext = __shfl_down(xx, 1, 64);
        if (lane == 63) Snext = 0;
        unsigned s3 = Snext + g[3];
        unsigned s2 = s3 + g[2];
        unsigned s1 = s2 + g[1];
        unsigned s0 = s1 + g[0];
        gsuf[4 * lane] = s0; gsuf[4 * lane + 1] = s1;
        gsuf[4 * lane + 2] = s2; gsuf[4 * lane + 3] = s3;
        if (lane == 63) gsuf[256] = 0;
    }
    __syncthreads();                                   // B2

    if (tid < 256) {
        unsigned above = gsuf[tid + 1];
        if (above < K_SEL && K_SEL <= gsuf[tid]) {
            unsigned running = above;
            for (int j = 7; j >= 0; j--) {
                unsigned c = binTot[tid * 8 + j];
                if (running < K_SEL && K_SEL <= running + c) {
                    uvar[0] = (unsigned)(tid * 8 + j);
                    uvar[1] = K_SEL - running;
                    break;
                }
                running += c;
            }
        }
    }
    __syncthreads();                                   // B3
    unsigned prefix = uvar[0];
    unsigned kk = uvar[1];

    // refine remaining 21 bits: 3 x 7-bit passes, wave-scan, 4 barriers each
    #pragma unroll
    for (int pass = 0; pass < 3; pass++) {
        const int shift = 14 - 7 * pass;       // 14, 7, 0
        if (tid < 128) h7[tid] = 0;
        __syncthreads();
        #pragma unroll
        for (int i = 0; i < 8; i++) {
            unsigned key = monokey(se[tid + i * 1024]);
            if ((key >> (shift + 7)) == prefix)
                atomicAdd(&h7[(key >> shift) & 127u], 1u);
        }
        __syncthreads();
        if (wid == 0) {
            unsigned a0 = h7[2 * lane];
            unsigned a1 = h7[2 * lane + 1];
            unsigned tot = a0 + a1;
            unsigned xx = tot;
            #pragma unroll
            for (int off = 1; off < 64; off <<= 1) {
                unsigned v = __shfl_down(xx, off, 64);
                if (lane + off < 64) xx += v;
            }
            unsigned Snext = __shfl_down(xx, 1, 64);
            if (lane == 63) Snext = 0;
            unsigned t1 = Snext + a1;
            unsigned t0 = t1 + a0;
            hsuf[2 * lane] = t0;
            hsuf[2 * lane + 1] = t1;
            if (lane == 63) hsuf[128] = 0;
        }
        __syncthreads();
        if (tid < 128) {
            unsigned above = hsuf[tid + 1];
            if (above < kk && kk <= hsuf[tid]) {
                uvar[0] = (prefix << 7) | (unsigned)tid;
                uvar[1] = kk - above;
            }
        }
        __syncthreads();
        prefix = uvar[0];
        kk = uvar[1];
    }
    const unsigned T = prefix;   // full key of k-th largest
    const unsigned r = kk;       // # of key==T inside top-k (global, position-ordered)

    // per-512-row-chunk tie counts -> quotas in ascending chunk order
    if (tid < NCH3) tie16[tid] = 0;
    __syncthreads();
    #pragma unroll
    for (int i = 0; i < 8; i++) {
        int s = i * 1024 + tid;
        unsigned long long beq = __ballot(monokey(se[s]) == T);
        if (lane == 0) atomicAdd(&tie16[s >> 9], (unsigned)__popcll(beq));
    }
    __syncthreads();
    if (tid == 0) {
        unsigned run = 0;
        unsigned* tq = tq_ws + b * 32;
        tq[0] = T;
        for (int c = 0; c < NCH3; c++) {
            unsigned tc = tie16[c];
            unsigned q = (r > run) ? (r - run) : 0u;
            if (q > tc) q = tc;
            tq[1 + c] = q;
            run += tc;
        }
    }
}

// ---- K3: fused ea-write + top-k correction (16 chunks/batch, 2 blocks/CU) ----
// corr[b,ch,d] = sum_{selected s in chunk} (0.5*a_s) * x[s,d]
__global__ __launch_bounds__(256) void k3_write_corr(const float* __restrict__ x,
                                                     const float* __restrict__ e_ws,
                                                     const unsigned* __restrict__ tq_ws,
                                                     const float* __restrict__ zinv,
                                                     float* __restrict__ ea_out,
                                                     float* __restrict__ corr) {
    const int b = blockIdx.x >> 4;
    const int ch = blockIdx.x & 15;
    const int tid = threadIdx.x;
    const int lane = tid & 63;
    const int wid = tid >> 6;

    const unsigned* tq = tq_ws + b * 32;
    const unsigned T = tq[0];
    const unsigned quota = tq[1 + ch];
    const float invZ = zinv[b];
    const int s0 = ch * CH3_ROWS;
    const float* eg = e_ws + (size_t)b * SS;
    float* og = ea_out + (size_t)b * SS;

    __shared__ int lidx[CH3_ROWS];      // 2 KB
    __shared__ float lw[CH3_ROWS];      // 2 KB
    __shared__ float lds[4 * 256];      // 4 KB
    __shared__ unsigned wtie[4];
    __shared__ unsigned tieRun;
    __shared__ unsigned selCnt;
    if (tid == 0) { tieRun = 0; selCnt = 0; }
    __syncthreads();

    #pragma unroll
    for (int i = 0; i < CH3_ROWS / 256; i++) {   // 2 iterations, position-ordered
        int s = s0 + i * 256 + tid;
        float v = eg[s];
        unsigned key = monokey(v);
        bool gt = key > T;
        bool eq = (key == T);
        unsigned long long beq = __ballot(eq);
        if (lane == 0) wtie[wid] = (unsigned)__popcll(beq);
        __syncthreads();
        unsigned base = tieRun;
        for (int w = 0; w < wid; w++) base += wtie[w];
        unsigned rank = base + (unsigned)__popcll(beq & ((1ull << lane) - 1ull));
        bool sel = gt || (eq && rank < quota);
        float a = expf(v) * invZ;
        og[s] = sel ? a * EMPH : a;
        if (sel) {
            unsigned slot = atomicAdd(&selCnt, 1u);   // ~100/block, parallel across 512 blocks
            lidx[slot] = s;
            lw[slot] = 0.5f * a;
        }
        __syncthreads();
        if (tid == 0) tieRun += wtie[0] + wtie[1] + wtie[2] + wtie[3];
        __syncthreads();
    }

    // gather phase: wave per row, full row = 64 lanes x float4; 2 rows in flight per wave
    const float* xb = x + (size_t)b * SS * DD;
    const unsigned n = selCnt;
    float4 acc0 = make_float4(0.f, 0.f, 0.f, 0.f);
    float4 acc1 = make_float4(0.f, 0.f, 0.f, 0.f);
    unsigned t = (unsigned)wid;
    for (; t + 4 < n; t += 8) {
        int sA = lidx[t];
        int sB = lidx[t + 4];
        float wA = lw[t];
        float wB = lw[t + 4];
        float4 a4 = ((const float4*)(xb + (size_t)sA * DD))[lane];
        float4 b4 = ((const float4*)(xb + (size_t)sB * DD))[lane];
        acc0.x += wA * a4.x; acc0.y += wA * a4.y; acc0.z += wA * a4.z; acc0.w += wA * a4.w;
        acc1.x += wB * b4.x; acc1.y += wB * b4.y; acc1.z += wB * b4.z; acc1.w += wB * b4.w;
    }
    if (t < n) {
        int sA = lidx[t];
        float wA = lw[t];
        float4 a4 = ((const float4*)(xb + (size_t)sA * DD))[lane];
        acc0.x += wA * a4.x; acc0.y += wA * a4.y; acc0.z += wA * a4.z; acc0.w += wA * a4.w;
    }
    acc0.x += acc1.x; acc0.y += acc1.y; acc0.z += acc1.z; acc0.w += acc1.w;

    ((float4*)lds)[wid * 64 + lane] = acc0;
    __syncthreads();
    float vv = lds[tid] + lds[256 + tid] + lds[512 + tid] + lds[768 + tid];
    corr[(size_t)blockIdx.x * DD + tid] = vv;
}

// ---- K6: out[b,d] = invZ * sum_ch s1part + sum_j corr ----
__global__ __launch_bounds__(256) void k6_final(const float* __restrict__ s1part,
                                                const float* __restrict__ corr,
                                                const float* __restrict__ zinv,
                                                float* __restrict__ out) {
    const int b = blockIdx.x;
    const int d = threadIdx.x;
    float s1 = 0.0f;
    #pragma unroll
    for (int ch = 0; ch < HCH; ch++) s1 += s1part[((size_t)b * HCH + ch) * DD + d];
    float c = 0.0f;
    #pragma unroll
    for (int j = 0; j < NCH3; j++) c += corr[((size_t)b * NCH3 + j) * DD + d];
    out[b * DD + d] = s1 * zinv[b] + c;
}

// ================= fallback path (round-1, verified; no ws needed) =================
__global__ __launch_bounds__(256) void f1_dot_tanh(const float* __restrict__ x,
                                                   const float* __restrict__ W,
                                                   const float* __restrict__ bias,
                                                   float* __restrict__ e) {
    const int lane = threadIdx.x & 63;
    const int wib  = threadIdx.x >> 6;
    const int waveId = blockIdx.x * 4 + wib;
    const int totalWaves = gridDim.x * 4;
    const float4 w4 = ((const float4*)W)[lane];
    const float bias0 = bias[0];
    for (int row = waveId; row < BB * SS; row += totalWaves) {
        float4 x4 = ((const float4*)(x + (size_t)row * DD))[lane];
        float p = x4.x * w4.x + x4.y * w4.y + x4.z * w4.z + x4.w * w4.w;
        #pragma unroll
        for (int off = 32; off >= 1; off >>= 1)
            p += __shfl_xor(p, off, 64);
        if (lane == 0) e[row] = tanhf(p + bias0);
    }
}
__global__ __launch_bounds__(1024) void f2_softmax_topk(float* __restrict__ ea) {
    const int b = blockIdx.x;
    const int tid = threadIdx.x;
    const int lane = tid & 63;
    const int wid  = tid >> 6;
    __shared__ float se[SS];
    __shared__ float wredf[16];
    __shared__ unsigned hist[256];
    __shared__ unsigned ssum[256];
    __shared__ unsigned wcnt[16];
    __shared__ unsigned uvar[3];
    __shared__ float fvar[1];
    float* eg = ea + (size_t)b * SS;
    float lsum = 0.0f;
    #pragma unroll
    for (int i = 0; i < 8; i++) {
        int s = tid + i * 1024;
        float v = eg[s];
        se[s] = v;
        lsum += expf(v);
    }
    #pragma unroll
    for (int off = 32; off >= 1; off >>= 1)
        lsum += __shfl_xor(lsum, off, 64);
    if (lane == 0) wredf[wid] = lsum;
    __syncthreads();
    if (tid == 0) {
        float z = 0.0f;
        for (int w = 0; w < 16; w++) z += wredf[w];
        fvar[0] = 1.0f / z;
    }
    __syncthreads();
    const float invZ = fvar[0];
    unsigned kk = K_SEL;
    unsigned prefix = 0;
    for (int byte = 3; byte >= 0; byte--) {
        if (tid < 256) hist[tid] = 0;
        __syncthreads();
        #pragma unroll
        for (int i = 0; i < 8; i++) {
            unsigned key = monokey(se[tid + i * 1024]);
            bool active = (byte == 3) || ((key >> ((byte + 1) * 8)) == prefix);
            if (active) atomicAdd(&hist[(key >> (byte * 8)) & 0xFFu], 1u);
        }
        __syncthreads();
        if (tid < 256) ssum[tid] = hist[tid];
        __syncthreads();
        for (int off = 1; off < 256; off <<= 1) {
            unsigned add = 0;
            if (tid < 256 && tid + off < 256) add = ssum[tid + off];
            __syncthreads();
            if (tid < 256) ssum[tid] += add;
            __syncthreads();
        }
        if (tid < 256) {
            unsigned above = (tid == 255) ? 0u : ssum[tid + 1];
            if (above < kk && kk <= ssum[tid]) {
                uvar[0] = (unsigned)tid;
                uvar[1] = kk - above;
            }
        }
        __syncthreads();
        prefix = (prefix << 8) | uvar[0];
        kk = uvar[1];
        __syncthreads();
    }
    const unsigned T = prefix;
    const unsigned r = kk;
    if (tid == 0) uvar[2] = 0;
    __syncthreads();
    for (int chunk = 0; chunk < 8; chunk++) {
        int s = chunk * 1024 + tid;
        float v = se[s];
        unsigned key = monokey(v);
        bool gt = key > T;
        bool eq = (key == T);
        unsigned long long bal = __ballot(eq);
        unsigned waveTot = (unsigned)__popcll(bal);
        unsigned myPref = (unsigned)__popcll(bal & ((1ull << lane) - 1ull));
        if (lane == 0) wcnt[wid] = waveTot;
        __syncthreads();
        unsigned base = uvar[2];
        for (int w = 0; w < wid; w++) base += wcnt[w];
        bool sel = gt || (eq && (base + myPref) < r);
        float a = expf(v) * invZ;
        eg[s] = sel ? a * EMPH : a;
        __syncthreads();
        if (tid == 0) {
            unsigned t = uvar[2];
            for (int w = 0; w < 16; w++) t += wcnt[w];
            uvar[2] = t;
        }
        __syncthreads();
    }
}
__global__ __launch_bounds__(256) void f0_zero(float* __restrict__ p, int n) {
    int i = blockIdx.x * blockDim.x + threadIdx.x;
    if (i < n) p[i] = 0.0f;
}
__global__ __launch_bounds__(256) void f3_weighted_atomic(const float* __restrict__ x,
                                                          const float* __restrict__ ea,
                                                          float* __restrict__ out) {
    const int blk = blockIdx.x;
    const int b = blk / NCHUNK;
    const int chunk = blk % NCHUNK;
    const int lane = threadIdx.x & 63;
    const int wid  = threadIdx.x >> 6;
    const float* xb = x + ((size_t)b * SS + (size_t)chunk * ROWS_PER_BLOCK) * DD;
    const float* ab = ea + (size_t)b * SS + (size_t)chunk * ROWS_PER_BLOCK;
    float4 acc = make_float4(0.f, 0.f, 0.f, 0.f);
    for (int rr = wid; rr < ROWS_PER_BLOCK; rr += 4) {
        float4 x4 = ((const float4*)(xb + (size_t)rr * DD))[lane];
        float a = ab[rr];
        acc.x += x4.x * a; acc.y += x4.y * a; acc.z += x4.z * a; acc.w += x4.w * a;
    }
    __shared__ float lds[4 * 256];
    ((float4*)lds)[wid * 64 + lane] = acc;
    __syncthreads();
    const int t = threadIdx.x;
    float v = lds[t] + lds[256 + t] + lds[512 + t] + lds[768 + t];
    atomicAdd(&out[b * 256 + t], v);
}

extern "C" void kernel_launch(void* const* d_in, const int* in_sizes, int n_in,
                              void* d_out, int out_size, void* d_ws, size_t ws_size,
                              hipStream_t stream) {
    (void)in_sizes; (void)n_in; (void)out_size;
    const float* x    = (const float*)d_in[0];
    const float* W    = (const float*)d_in[1];
    const float* bias = (const float*)d_in[2];
    float* out = (float*)d_out;
    float* sum_out = out;             // [B, D]
    float* ea = out + BB * DD;        // [B, S]

    const size_t e_bytes    = (size_t)BB * SS * sizeof(float);                 // 1 MB
    const size_t hist_bytes = (size_t)BB * HCH * HBINS * sizeof(unsigned);     // 2 MB
    const size_t s1_bytes   = (size_t)BB * HCH * DD * sizeof(float);           // 256 KB
    const size_t corr_bytes = (size_t)BB * NCH3 * DD * sizeof(float);          // 512 KB
    const size_t zinv_bytes = 128;
    const size_t zpart_bytes= (size_t)BB * HCH * sizeof(float);                // 1 KB
    const size_t tq_bytes   = (size_t)BB * 32 * sizeof(unsigned);              // 4 KB
    const size_t need = e_bytes + hist_bytes + s1_bytes + corr_bytes + zinv_bytes
                      + zpart_bytes + tq_bytes;

    if (ws_size >= need) {
        char* p = (char*)d_ws;
        float*    e_ws    = (float*)p;                 p += e_bytes;
        unsigned* hist_ws = (unsigned*)p;              p += hist_bytes;
        float*    s1part  = (float*)p;                 p += s1_bytes;
        float*    corr    = (float*)p;                 p += corr_bytes;
        float*    zinv    = (float*)p;                 p += zinv_bytes;
        float*    zpart   = (float*)p;                 p += zpart_bytes;
        unsigned* tq_ws   = (unsigned*)p;

        k1_e_hist_s1<<<BB * HCH, 1024, 0, stream>>>(x, W, bias, e_ws, hist_ws, s1part, zpart);
        k2_thresh<<<BB, 1024, 0, stream>>>(e_ws, hist_ws, zpart, zinv, tq_ws);
        k3_write_corr<<<BB * NCH3, 256, 0, stream>>>(x, e_ws, tq_ws, zinv, ea, corr);
        k6_final<<<BB, 256, 0, stream>>>(s1part, corr, zinv, sum_out);
    } else {
        f1_dot_tanh<<<4096, 256, 0, stream>>>(x, W, bias, ea);
        f2_softmax_topk<<<BB, 1024, 0, stream>>>(ea);
        f0_zero<<<(BB * DD + 255) / 256, 256, 0, stream>>>(sum_out, BB * DD);
        f3_weighted_atomic<<<BB * NCHUNK, 256, 0, stream>>>(x, ea, sum_out);
    }
}